// Round 1
// baseline (942.132 us; speedup 1.0000x reference)
//
#include <hip/hip_runtime.h>
#include <math.h>

#define B 64
#define P 24564
#define NC 81
#define T 24

static constexpr size_t BP = (size_t)B * P;  // 1,572,096
// workspace layout (bytes)
static constexpr size_t OFF_CLOSS  = 0;                       // float[BP]
static constexpr size_t OFF_BPK    = 4 * BP;                  // u64[B*T]
static constexpr size_t OFF_NUMPOS = OFF_BPK + 8 * (size_t)(B * T); // int[64]
static constexpr size_t OFF_ACC    = OFF_NUMPOS + 256;        // double[3]

__device__ inline float sl1(float d) {
    float ad = fabsf(d);
    return (ad < 1.0f) ? 0.5f * d * d : ad - 0.5f;
}

__device__ inline void gl_lds16(const float* g, float* l) {
    __builtin_amdgcn_global_load_lds((const __attribute__((address_space(1))) void*)g,
                                     (__attribute__((address_space(3))) void*)l, 16, 0, 0);
}

// K0: init bpk keys + zero numPos/acc
__global__ void k_init(unsigned long long* __restrict__ bpk,
                       int* __restrict__ numPos, double* __restrict__ acc) {
    int i = blockIdx.x * 256 + threadIdx.x;
    if (i < B * T) bpk[i] = 0xFFFFFFFFull;  // iou=0, prior 0
    if (i < B) numPos[i] = 0;
    if (i < 3) acc[i] = 0.0;
}

// K1 (merged): phase 1 computes IOUs once — per-thread best-truth AND per-truth
// best-prior (wave reduce + ballot + u64 atomicMax into bpk). ph-branch priors
// (best_truth_overlap <= 0.5 best-priors, <= B*T of them) are repaired by k_fix.
// Phase 2: LDS-staged conf lse scan (per-wave dbuf) unchanged.
__global__ __launch_bounds__(256) void k_main(
        const float* __restrict__ loc, const float* __restrict__ conf,
        const float* __restrict__ targets, const float* __restrict__ anchors,
        unsigned long long* __restrict__ bpk,
        float* __restrict__ closs, int* __restrict__ numPos, double* __restrict__ acc) {
    __shared__ float stage[4][2][16 * NC];  // 41472 B, per-wave double buffer
    __shared__ float tg[T * 5];
    __shared__ double sdl[4], sdc[4];
    __shared__ int spc[4];

    int b = blockIdx.y;
    int tid = threadIdx.x, lane = tid & 63, w = tid >> 6;
    int p = blockIdx.x * 256 + tid;
    size_t rowBase = (size_t)b * P;

    if (tid < T * 5) tg[tid] = targets[(size_t)b * T * 5 + tid];
    __syncthreads();

    bool valid = p < P;
    int lbl = 0;
    float locC = 0.0f;
    float4 a = make_float4(0.0f, 0.0f, 1.0f, 1.0f);
    float ax1 = 0, ay1 = 0, ax2 = 0, ay2 = 0, aarea = 0;
    if (valid) {
        a = ((const float4*)anchors)[p];
        ax1 = a.x - a.z * 0.5f; ay1 = a.y - a.w * 0.5f;
        ax2 = a.x + a.z * 0.5f; ay2 = a.y + a.w * 0.5f;
        aarea = (ax2 - ax1) * (ay2 - ay1);
    }
    int waveP0 = blockIdx.x * 256 + (tid & ~63);
    float bestOv = -1.0f; int bestT = 0;
    #pragma unroll 4
    for (int t = 0; t < T; ++t) {
        float tx1 = tg[t * 5 + 0], ty1 = tg[t * 5 + 1];
        float tx2 = tg[t * 5 + 2], ty2 = tg[t * 5 + 3];
        float iou = 0.0f;
        if (valid) {
            float lx = fmaxf(tx1, ax1), ly = fmaxf(ty1, ay1);
            float rx = fminf(tx2, ax2), ry = fminf(ty2, ay2);
            float ww = fmaxf(rx - lx, 0.0f), hh = fmaxf(ry - ly, 0.0f);
            float inter = ww * hh;
            float ta = (tx2 - tx1) * (ty2 - ty1);
            iou = inter / (ta + aarea - inter);
        }
        if (iou > bestOv) { bestOv = iou; bestT = t; }  // first-occurrence argmax
        // per-truth best-prior wave reduce (formerly k_match)
        float mx = iou;
        #pragma unroll
        for (int off = 1; off < 64; off <<= 1) mx = fmaxf(mx, __shfl_xor(mx, off, 64));
        unsigned long long bal = __ballot(iou == mx);
        if (lane == 0 && mx > 0.0f) {
            int src = __ffsll((unsigned long long)bal) - 1;  // lowest lane = lowest p
            unsigned int bp = (unsigned)(waveP0 + src);
            unsigned long long key = ((unsigned long long)__float_as_uint(mx) << 32)
                                   | (unsigned long long)(0xFFFFFFFFu - bp);
            atomicMax(&bpk[b * T + t], key);
        }
    }
    if (valid && bestOv > 0.5f) {
        int tIdx = bestT;
        float x1 = tg[tIdx * 5 + 0], y1 = tg[tIdx * 5 + 1];
        float x2 = tg[tIdx * 5 + 2], y2 = tg[tIdx * 5 + 3];
        lbl = (int)tg[tIdx * 5 + 4];  // >= 1
        float cx = (x1 + x2) * 0.5f, cy = (y1 + y2) * 0.5f;
        float ww = x2 - x1, hh = y2 - y1;
        float e0 = (cx - a.x) / a.z;
        float e1 = (cy - a.y) / a.w;
        float e2 = logf(ww) - logf(a.z);
        float e3 = logf(hh) - logf(a.w);
        float4 lp = ((const float4*)loc)[rowBase + p];
        locC = sl1(lp.x - e0) + sl1(lp.y - e1) + sl1(lp.z - e2) + sl1(lp.w - e3);
    }

    // ---- phase 2: conf rows [R0, R0+64), 4 stages x 16 rows, per-wave dbuf ----
    const int R0 = blockIdx.x * 256 + w * 64;
    const int r = lane >> 2, q = lane & 3;
    float* sb0 = &stage[w][0][0];
    float* sb1 = &stage[w][1][0];
    const float* gconf = conf + rowBase * (size_t)NC;
    double clsAcc = 0.0;
    float clv[4];
    bool clw[4];

    {   // prologue: stage 0
        int srcRow = R0 > P - 16 ? P - 16 : R0;
        const float* g = gconf + (size_t)srcRow * NC;
        #pragma unroll
        for (int kk = 0; kk < 5; ++kk) gl_lds16(g + kk * 256 + lane * 4, sb0 + kk * 256);
        if (lane < 4) gl_lds16(g + 1280 + lane * 4, sb0 + 1280);
    }
    #pragma unroll
    for (int s = 0; s < 4; ++s) {
        float* cur = (s & 1) ? sb1 : sb0;
        float* nxt = (s & 1) ? sb0 : sb1;
        if (s < 3) {
            int nRow = R0 + (s + 1) * 16;
            int srcRow = nRow > P - 16 ? P - 16 : nRow;
            const float* g = gconf + (size_t)srcRow * NC;
            __builtin_amdgcn_s_waitcnt(0xC07F);  // lgkmcnt(0): prior stage's ds_reads retired
            #pragma unroll
            for (int kk = 0; kk < 5; ++kk) gl_lds16(g + kk * 256 + lane * 4, nxt + kk * 256);
            if (lane < 4) gl_lds16(g + 1280 + lane * 4, nxt + 1280);
            __builtin_amdgcn_s_waitcnt(0x0F76);  // vmcnt(6): cur stage DMA complete
        } else {
            __builtin_amdgcn_s_waitcnt(0x0F70);  // vmcnt(0)
        }
        int stageRow = R0 + s * 16;
        int srcRow = stageRow > P - 16 ? P - 16 : stageRow;
        int ldsRow = r + (stageRow - srcRow);
        bool rowValid = ldsRow < 16;             // <=> (stageRow + r) < P
        int ldsRowC = rowValid ? ldsRow : 15;
        int lblRow = __shfl(lbl, s * 16 + r, 64);
        const float* rp = cur + ldsRowC * NC;
        float s0 = 0.0f;
        #pragma unroll
        for (int k = 0; k < 20; ++k) s0 += __expf(rp[q + 4 * k]);
        float x0 = 0.0f, xs = 0.0f;
        if (q == 0) { x0 = rp[0]; s0 += __expf(rp[80]); }
        if ((lblRow & 3) == q) xs = rp[lblRow];
        s0 += __shfl_xor(s0, 1, 64);
        s0 += __shfl_xor(s0, 2, 64);
        xs += __shfl_xor(xs, 1, 64);
        xs += __shfl_xor(xs, 2, 64);
        float lse = __logf(s0);
        bool pos = lblRow > 0;
        clw[s] = (q == 0) && rowValid;
        clv[s] = pos ? 0.0f : fmaxf(lse - x0, 0.0f);
        if (clw[s] && pos) clsAcc += (double)(lse - xs);
    }
    #pragma unroll
    for (int s = 0; s < 4; ++s)
        if (clw[s]) closs[rowBase + R0 + s * 16 + r] = clv[s];

    // ---- block reduction -> global atomics ----
    double dl = (double)locC, dc = clsAcc;
    int pc = (lbl > 0) ? 1 : 0;
    #pragma unroll
    for (int off = 32; off > 0; off >>= 1) {
        dl += __shfl_down(dl, off, 64);
        dc += __shfl_down(dc, off, 64);
        pc += __shfl_down(pc, off, 64);
    }
    if (lane == 0) { sdl[w] = dl; sdc[w] = dc; spc[w] = pc; }
    __syncthreads();
    if (tid == 0) {
        atomicAdd(&acc[0], sdl[0] + sdl[1] + sdl[2] + sdl[3]);
        atomicAdd(&acc[1], sdc[0] + sdc[1] + sdc[2] + sdc[3]);
        atomicAdd(&numPos[b], spc[0] + spc[1] + spc[2] + spc[3]);
    }
}

// K_fix: repair the ph-branch priors (best-prior of some truth with
// best_truth_overlap <= 0.5). <= B*T priors total. Replays k_main's exact FP
// expression order so deltas are bitwise what the fused path would produce.
__global__ __launch_bounds__(128) void k_fix(
        const float* __restrict__ loc, const float* __restrict__ conf,
        const float* __restrict__ targets, const float* __restrict__ anchors,
        const unsigned long long* __restrict__ bpk,
        float* __restrict__ closs, int* __restrict__ numPos, double* __restrict__ acc) {
    int b = blockIdx.x;
    int tid = threadIdx.x;
    __shared__ float tg[T * 5];
    __shared__ unsigned int bpS[T];
    if (tid < T * 5) tg[tid] = targets[(size_t)b * T * 5 + tid];
    if (tid >= 96 && tid < 96 + T)
        bpS[tid - 96] = 0xFFFFFFFFu - (unsigned)(bpk[b * T + tid - 96] & 0xFFFFFFFFull);
    __syncthreads();
    double dLoc = 0.0, dCls = 0.0;
    int dPos = 0;
    if (tid < T) {
        int t = tid;
        unsigned int pp = bpS[t];
        bool owner = true;                        // last t with this prior wins
        for (int t2 = t + 1; t2 < T; ++t2) if (bpS[t2] == pp) owner = false;
        if (owner) {
            float4 a = ((const float4*)anchors)[pp];
            float ax1 = a.x - a.z * 0.5f, ay1 = a.y - a.w * 0.5f;
            float ax2 = a.x + a.z * 0.5f, ay2 = a.y + a.w * 0.5f;
            float aarea = (ax2 - ax1) * (ay2 - ay1);
            float bestOv = -1.0f;
            for (int t2 = 0; t2 < T; ++t2) {
                float tx1 = tg[t2 * 5 + 0], ty1 = tg[t2 * 5 + 1];
                float tx2 = tg[t2 * 5 + 2], ty2 = tg[t2 * 5 + 3];
                float lx = fmaxf(tx1, ax1), ly = fmaxf(ty1, ay1);
                float rx = fminf(tx2, ax2), ry = fminf(ty2, ay2);
                float ww = fmaxf(rx - lx, 0.0f), hh = fmaxf(ry - ly, 0.0f);
                float inter = ww * hh;
                float ta = (tx2 - tx1) * (ty2 - ty1);
                float iou = inter / (ta + aarea - inter);
                if (iou > bestOv) bestOv = iou;
            }
            if (!(bestOv > 0.5f)) {
                // ph branch: label/encode from truth t vs anchor pp
                float x1 = tg[t * 5 + 0], y1 = tg[t * 5 + 1];
                float x2 = tg[t * 5 + 2], y2 = tg[t * 5 + 3];
                int lbl = (int)tg[t * 5 + 4];     // >= 1
                float cx = (x1 + x2) * 0.5f, cy = (y1 + y2) * 0.5f;
                float ww = x2 - x1, hh = y2 - y1;
                float e0 = (cx - a.x) / a.z;
                float e1 = (cy - a.y) / a.w;
                float e2 = logf(ww) - logf(a.z);
                float e3 = logf(hh) - logf(a.w);
                float4 lp = ((const float4*)loc)[(size_t)b * P + pp];
                float locC = sl1(lp.x - e0) + sl1(lp.y - e1) + sl1(lp.z - e2) + sl1(lp.w - e3);
                dLoc = (double)locC;
                dPos = 1;
                const float* c = conf + ((size_t)b * P + pp) * (size_t)NC;
                float s0 = 0.0f, s1 = 0.0f, s2 = 0.0f, s3 = 0.0f;
                #pragma unroll
                for (int k = 0; k < 20; ++k) {
                    s0 += __expf(c[4 * k + 0]);
                    s1 += __expf(c[4 * k + 1]);
                    s2 += __expf(c[4 * k + 2]);
                    s3 += __expf(c[4 * k + 3]);
                }
                s0 += __expf(c[80]);
                float lse = __logf((s0 + s1) + (s2 + s3));  // k_main's pairwise order
                float xs = c[lbl];
                dCls = (double)(lse - xs);
                closs[(size_t)b * P + pp] = 0.0f;  // pos prior -> closs 0 (matches ref)
            }
        }
    }
    // wave-0 reduce (deltas live in lanes 0..23 only)
    #pragma unroll
    for (int off = 32; off > 0; off >>= 1) {
        dLoc += __shfl_down(dLoc, off, 64);
        dCls += __shfl_down(dCls, off, 64);
        dPos += __shfl_down(dPos, off, 64);
    }
    if (tid == 0) {
        if (dLoc != 0.0) atomicAdd(&acc[0], dLoc);
        if (dCls != 0.0) atomicAdd(&acc[1], dCls);
        if (dPos) atomicAdd(&numPos[b], dPos);
    }
}

// K3: per-batch radix-select K-th largest closs, sum of top-K (tie-invariant)
__global__ __launch_bounds__(1024) void k_select(
        const float* __restrict__ closs, const int* __restrict__ numPos,
        double* __restrict__ acc) {
    int b = blockIdx.x;
    int tid = threadIdx.x;
    int np = numPos[b];
    long long Kl = 3LL * np;
    int K = (int)(Kl < (long long)(P - 1) ? Kl : (long long)(P - 1));
    if (K <= 0) return;
    const float* row = closs + (size_t)b * P;
    __shared__ unsigned int hist[256];
    __shared__ unsigned int s_prefix;
    __shared__ int s_rem;
    __shared__ double sred[16];
    __shared__ int cred[16];
    if (tid == 0) { s_prefix = 0; s_rem = K; }
    __syncthreads();
    for (int rd = 3; rd >= 0; --rd) {
        if (tid < 256) hist[tid] = 0;
        __syncthreads();
        unsigned int prefix = s_prefix;
        int rem = s_rem;
        for (int i = tid; i < P; i += 1024) {
            unsigned int bits = __float_as_uint(row[i]);
            if (rd == 3 || (bits >> ((rd + 1) * 8)) == prefix)
                atomicAdd(&hist[(bits >> (rd * 8)) & 0xFFu], 1u);
        }
        __syncthreads();
        if (tid < 64) {
            unsigned int h0 = hist[4 * tid + 0], h1 = hist[4 * tid + 1];
            unsigned int h2 = hist[4 * tid + 2], h3 = hist[4 * tid + 3];
            unsigned int S = h0 + h1 + h2 + h3;
            #pragma unroll
            for (int off = 1; off < 64; off <<= 1) {   // inclusive suffix scan
                unsigned int up = __shfl_down(S, off, 64);
                if (tid + off < 64) S += up;
            }
            unsigned int above = __shfl_down(S, 1, 64);
            if (tid == 63) above = 0;
            if ((unsigned)rem <= S && (unsigned)rem > above) {
                int rr = rem - (int)above;
                int digit;
                if (rr <= (int)h3) digit = 4 * tid + 3;
                else { rr -= h3;
                    if (rr <= (int)h2) digit = 4 * tid + 2;
                    else { rr -= h2;
                        if (rr <= (int)h1) digit = 4 * tid + 1;
                        else { rr -= h1; digit = 4 * tid; } } }
                s_prefix = (prefix << 8) | (unsigned)digit;
                s_rem = rr;
            }
        }
        __syncthreads();
    }
    unsigned int tbits = s_prefix;
    float tval = __uint_as_float(tbits);
    int cg = 0;
    double sg = 0.0;
    for (int i = tid; i < P; i += 1024) {
        float v = row[i];
        if (__float_as_uint(v) > tbits) { cg++; sg += (double)v; }
    }
    int lane = tid & 63, w = tid >> 6;
    #pragma unroll
    for (int off = 32; off > 0; off >>= 1) {
        sg += __shfl_down(sg, off, 64);
        cg += __shfl_down(cg, off, 64);
    }
    if (lane == 0) { sred[w] = sg; cred[w] = cg; }
    __syncthreads();
    if (tid == 0) {
        double sgT = 0.0; int cgT = 0;
        #pragma unroll
        for (int i = 0; i < 16; ++i) { sgT += sred[i]; cgT += cred[i]; }
        atomicAdd(&acc[2], sgT + (double)(K - cgT) * (double)tval);
    }
}

// K4: finalize
__global__ void k_final(const int* __restrict__ numPos, const double* __restrict__ acc,
                        float* __restrict__ out) {
    int lane = threadIdx.x;  // 64 threads, B=64
    int np = numPos[lane];
    long long Kl = 3LL * np;
    long long K = Kl < (long long)(P - 1) ? Kl : (long long)(P - 1);
    long long sel = (long long)np + K;  // pos/neg disjoint
    int N = np;
    #pragma unroll
    for (int off = 32; off > 0; off >>= 1) {
        N += __shfl_down(N, off, 64);
        sel += __shfl_down(sel, off, 64);
    }
    if (lane == 0) {
        double n = (double)N;
        double nonsel = (double)((long long)B * (long long)P - sel);
        double cls = acc[1] + acc[2] + nonsel * 4.3944491546724391;  // ln(81)
        out[0] = (float)(acc[0] / n);
        out[1] = (float)(cls / n);
    }
}

extern "C" void kernel_launch(void* const* d_in, const int* in_sizes, int n_in,
                              void* d_out, int out_size, void* d_ws, size_t ws_size,
                              hipStream_t stream) {
    const float* loc     = (const float*)d_in[0];
    const float* conf    = (const float*)d_in[1];
    const float* targets = (const float*)d_in[2];
    const float* anchors = (const float*)d_in[3];
    float* out = (float*)d_out;
    char* ws = (char*)d_ws;

    float* closs  = (float*)(ws + OFF_CLOSS);
    unsigned long long* bpk = (unsigned long long*)(ws + OFF_BPK);
    int* numPos   = (int*)(ws + OFF_NUMPOS);
    double* acc   = (double*)(ws + OFF_ACC);

    k_init<<<6, 256, 0, stream>>>(bpk, numPos, acc);
    dim3 g1((P + 255) / 256, B);
    k_main<<<g1, 256, 0, stream>>>(loc, conf, targets, anchors, bpk,
                                   closs, numPos, acc);
    k_fix<<<B, 128, 0, stream>>>(loc, conf, targets, anchors, bpk,
                                 closs, numPos, acc);
    k_select<<<B, 1024, 0, stream>>>(closs, numPos, acc);
    k_final<<<1, 64, 0, stream>>>(numPos, acc, out);
}

// Round 3
// 782.412 us; speedup vs baseline: 1.2041x; 1.2041x over previous
//
#include <hip/hip_runtime.h>
#include <math.h>

#define B 64
#define P 24564
#define NC 81
#define T 24

static constexpr size_t BP = (size_t)B * P;  // 1,572,096
// workspace layout (bytes)
static constexpr size_t OFF_CLOSS  = 0;                       // float[BP]
static constexpr size_t OFF_BPK    = 4 * BP;                  // u64[B*T]
static constexpr size_t OFF_NUMPOS = OFF_BPK + 8 * (size_t)(B * T); // int[64]
static constexpr size_t OFF_ACC    = OFF_NUMPOS + 256;        // double[3]

__device__ inline float sl1(float d) {
    float ad = fabsf(d);
    return (ad < 1.0f) ? 0.5f * d * d : ad - 0.5f;
}

__device__ inline void gl_lds16(const float* g, float* l) {
    __builtin_amdgcn_global_load_lds((const __attribute__((address_space(1))) void*)g,
                                     (__attribute__((address_space(3))) void*)l, 16, 0, 0);
}

// K0: init bpk keys + zero numPos/acc
__global__ void k_init(unsigned long long* __restrict__ bpk,
                       int* __restrict__ numPos, double* __restrict__ acc) {
    int i = blockIdx.x * 256 + threadIdx.x;
    if (i < B * T) bpk[i] = 0xFFFFFFFFull;  // iou=0, prior 0
    if (i < B) numPos[i] = 0;
    if (i < 3) acc[i] = 0.0;
}

// K1: fused match + loc loss + conf lse scan.
//  - 8-row conf stages (649 used floats padded to 768), per-wave dbuf -> ~25 KB LDS
//    -> 6 blocks/CU (24 waves) vs old 3 blocks (12 waves).
//  - stage-0/1 DMA issued BEFORE phase 1 so IOU/reduce compute hides DMA latency.
//  - phase-1 per-truth winner: branch-free (lane==t keeps key), ONE tail atomic.
__global__ __launch_bounds__(256) void k_main(
        const float* __restrict__ loc, const float* __restrict__ conf,
        const float* __restrict__ targets, const float* __restrict__ anchors,
        unsigned long long* __restrict__ bpk,
        float* __restrict__ closs, int* __restrict__ numPos, double* __restrict__ acc) {
    __shared__ float stage[4][2][768];  // 24576 B; 8 rows * 81 floats used + pad
    __shared__ float tg[T * 5];
    __shared__ double sdl[4], sdc[4];
    __shared__ int spc[4];

    int b = blockIdx.y;
    int tid = threadIdx.x, lane = tid & 63, w = tid >> 6;
    int p = blockIdx.x * 256 + tid;
    size_t rowBase = (size_t)b * P;

    if (tid < T * 5) tg[tid] = targets[(size_t)b * T * 5 + tid];
    __syncthreads();   // no DMA outstanding yet -> barrier drain is cheap

    // ---- issue conf DMA for stages 0,1 first: latency hides under phase 1 ----
    const int R0 = blockIdx.x * 256 + w * 64;   // wave's 64 conf rows
    const float* gconf = conf + rowBase * (size_t)NC;
    float* sb0 = &stage[w][0][0];
    float* sb1 = &stage[w][1][0];
    // tail DMA call: lanes >=34 re-read g+512 (coalesces to 1 line) and land in pad
    int l2 = lane < 34 ? lane : 0;
    {
        int sr0 = R0     > P - 8 ? P - 8 : R0;
        int sr1 = R0 + 8 > P - 8 ? P - 8 : R0 + 8;
        const float* g0 = gconf + (size_t)sr0 * NC;
        const float* g1 = gconf + (size_t)sr1 * NC;
        gl_lds16(g0 + lane * 4, sb0);
        gl_lds16(g0 + 256 + lane * 4, sb0 + 256);
        gl_lds16(g0 + 512 + l2 * 4, sb0 + 512);
        gl_lds16(g1 + lane * 4, sb1);
        gl_lds16(g1 + 256 + lane * 4, sb1 + 256);
        gl_lds16(g1 + 512 + l2 * 4, sb1 + 512);
    }

    // ---- phase 1: IOU, per-thread best-truth, per-truth best-prior ----
    bool valid = p < P;
    int lbl = 0;
    float locC = 0.0f;
    float4 a = make_float4(0.0f, 0.0f, 1.0f, 1.0f);
    float ax1 = 0, ay1 = 0, ax2 = 0, ay2 = 0, aarea = 0;
    if (valid) {
        a = ((const float4*)anchors)[p];
        ax1 = a.x - a.z * 0.5f; ay1 = a.y - a.w * 0.5f;
        ax2 = a.x + a.z * 0.5f; ay2 = a.y + a.w * 0.5f;
        aarea = (ax2 - ax1) * (ay2 - ay1);
    }
    int waveP0 = blockIdx.x * 256 + (tid & ~63);
    float bestOv = -1.0f; int bestT = 0;
    unsigned long long myKey = 0;   // lane t holds winner key for truth t
    #pragma unroll 4
    for (int t = 0; t < T; ++t) {
        float tx1 = tg[t * 5 + 0], ty1 = tg[t * 5 + 1];
        float tx2 = tg[t * 5 + 2], ty2 = tg[t * 5 + 3];
        float iou = 0.0f;
        if (valid) {
            float lx = fmaxf(tx1, ax1), ly = fmaxf(ty1, ay1);
            float rx = fminf(tx2, ax2), ry = fminf(ty2, ay2);
            float ww = fmaxf(rx - lx, 0.0f), hh = fmaxf(ry - ly, 0.0f);
            float inter = ww * hh;
            float ta = (tx2 - tx1) * (ty2 - ty1);
            iou = inter / (ta + aarea - inter);
        }
        if (iou > bestOv) { bestOv = iou; bestT = t; }  // first-occurrence argmax
        float mx = iou;
        #pragma unroll
        for (int off = 1; off < 64; off <<= 1) mx = fmaxf(mx, __shfl_xor(mx, off, 64));
        unsigned long long bal = __ballot(iou == mx);
        int src = __ffsll(bal) - 1;                     // lowest lane = lowest p
        unsigned int bp = (unsigned)(waveP0 + src);
        unsigned long long key = ((unsigned long long)__float_as_uint(mx) << 32)
                               | (unsigned long long)(0xFFFFFFFFu - bp);
        if (lane == t) myKey = key;                     // cndmask, no branch
    }
    if (lane < T) atomicMax(&bpk[b * T + lane], myKey); // one vector atomic
    if (valid && bestOv > 0.5f) {
        int tIdx = bestT;
        float x1 = tg[tIdx * 5 + 0], y1 = tg[tIdx * 5 + 1];
        float x2 = tg[tIdx * 5 + 2], y2 = tg[tIdx * 5 + 3];
        lbl = (int)tg[tIdx * 5 + 4];  // >= 1
        float cx = (x1 + x2) * 0.5f, cy = (y1 + y2) * 0.5f;
        float ww = x2 - x1, hh = y2 - y1;
        float e0 = (cx - a.x) / a.z;
        float e1 = (cy - a.y) / a.w;
        float e2 = logf(ww) - logf(a.z);
        float e3 = logf(hh) - logf(a.w);
        float4 lp = ((const float4*)loc)[rowBase + p];
        locC = sl1(lp.x - e0) + sl1(lp.y - e1) + sl1(lp.z - e2) + sl1(lp.w - e3);
    }

    // ---- phase 2: 8 stages x 8 rows, 8 lanes/row, per-wave dbuf, vmcnt(3) ----
    const int r = lane >> 3, q = lane & 7;
    double clsAcc = 0.0;
    float clv[8];
    unsigned int clwMask = 0;
    #pragma unroll
    for (int s = 0; s < 8; ++s) {
        float* cur = (s & 1) ? sb1 : sb0;
        if (s < 7) {
            __builtin_amdgcn_s_waitcnt(0x0F73);  // vmcnt(3): cur stage DMA done
        } else {
            __builtin_amdgcn_s_waitcnt(0x0F70);  // vmcnt(0)
        }
        int stageRow = R0 + s * 8;
        int srcRow = stageRow > P - 8 ? P - 8 : stageRow;
        int ldsRow = r + (stageRow - srcRow);
        bool rowValid = ldsRow < 8;              // <=> (stageRow + r) < P
        int ldsRowC = rowValid ? ldsRow : 7;
        int lblRow = __shfl(lbl, s * 8 + r, 64);
        const float* rp = cur + ldsRowC * NC;
        float s0 = 0.0f;
        #pragma unroll
        for (int k = 0; k < 10; ++k) s0 += __expf(rp[q + 8 * k]);
        float x0 = 0.0f, xs = 0.0f;
        if (q == 0) { x0 = rp[0]; s0 += __expf(rp[80]); }
        if ((lblRow & 7) == q) xs = rp[lblRow];
        s0 += __shfl_xor(s0, 1, 64);
        s0 += __shfl_xor(s0, 2, 64);
        s0 += __shfl_xor(s0, 4, 64);
        xs += __shfl_xor(xs, 1, 64);
        xs += __shfl_xor(xs, 2, 64);
        xs += __shfl_xor(xs, 4, 64);
        float lse = __logf(s0);
        bool pos = lblRow > 0;
        bool clw = (q == 0) && rowValid;
        clv[s] = pos ? 0.0f : fmaxf(lse - x0, 0.0f);
        if (clw) clwMask |= 1u << s;
        if (clw && pos) clsAcc += (double)(lse - xs);
        if (s < 6) {   // prefetch stage s+2 into the buffer just consumed
            __builtin_amdgcn_s_waitcnt(0xC07F);  // lgkmcnt(0): ds_reads retired
            int nsr = R0 + (s + 2) * 8; nsr = nsr > P - 8 ? P - 8 : nsr;
            const float* g = gconf + (size_t)nsr * NC;
            gl_lds16(g + lane * 4, cur);
            gl_lds16(g + 256 + lane * 4, cur + 256);
            gl_lds16(g + 512 + l2 * 4, cur + 512);
        }
    }
    #pragma unroll
    for (int s = 0; s < 8; ++s)
        if (clwMask & (1u << s)) closs[rowBase + R0 + s * 8 + r] = clv[s];

    // ---- block reduction -> global atomics ----
    double dl = (double)locC, dc = clsAcc;
    int pc = (lbl > 0) ? 1 : 0;
    #pragma unroll
    for (int off = 32; off > 0; off >>= 1) {
        dl += __shfl_down(dl, off, 64);
        dc += __shfl_down(dc, off, 64);
        pc += __shfl_down(pc, off, 64);
    }
    if (lane == 0) { sdl[w] = dl; sdc[w] = dc; spc[w] = pc; }
    __syncthreads();
    if (tid == 0) {
        atomicAdd(&acc[0], sdl[0] + sdl[1] + sdl[2] + sdl[3]);
        atomicAdd(&acc[1], sdc[0] + sdc[1] + sdc[2] + sdc[3]);
        atomicAdd(&numPos[b], spc[0] + spc[1] + spc[2] + spc[3]);
    }
}

// K_fix: repair the ph-branch priors (best-prior of some truth with
// best_truth_overlap <= 0.5). <= B*T priors total. Same IOU expression order
// as k_main so the >0.5 decision is bitwise-consistent.
__global__ __launch_bounds__(128) void k_fix(
        const float* __restrict__ loc, const float* __restrict__ conf,
        const float* __restrict__ targets, const float* __restrict__ anchors,
        const unsigned long long* __restrict__ bpk,
        float* __restrict__ closs, int* __restrict__ numPos, double* __restrict__ acc) {
    int b = blockIdx.x;
    int tid = threadIdx.x;
    __shared__ float tg[T * 5];
    __shared__ unsigned int bpS[T];
    if (tid < T * 5) tg[tid] = targets[(size_t)b * T * 5 + tid];
    if (tid >= 96 && tid < 96 + T)
        bpS[tid - 96] = 0xFFFFFFFFu - (unsigned)(bpk[b * T + tid - 96] & 0xFFFFFFFFull);
    __syncthreads();
    double dLoc = 0.0, dCls = 0.0;
    int dPos = 0;
    if (tid < T) {
        int t = tid;
        unsigned int pp = bpS[t];
        bool owner = true;                        // last t with this prior wins
        for (int t2 = t + 1; t2 < T; ++t2) if (bpS[t2] == pp) owner = false;
        if (owner) {
            float4 a = ((const float4*)anchors)[pp];
            float ax1 = a.x - a.z * 0.5f, ay1 = a.y - a.w * 0.5f;
            float ax2 = a.x + a.z * 0.5f, ay2 = a.y + a.w * 0.5f;
            float aarea = (ax2 - ax1) * (ay2 - ay1);
            float bestOv = -1.0f;
            for (int t2 = 0; t2 < T; ++t2) {
                float tx1 = tg[t2 * 5 + 0], ty1 = tg[t2 * 5 + 1];
                float tx2 = tg[t2 * 5 + 2], ty2 = tg[t2 * 5 + 3];
                float lx = fmaxf(tx1, ax1), ly = fmaxf(ty1, ay1);
                float rx = fminf(tx2, ax2), ry = fminf(ty2, ay2);
                float ww = fmaxf(rx - lx, 0.0f), hh = fmaxf(ry - ly, 0.0f);
                float inter = ww * hh;
                float ta = (tx2 - tx1) * (ty2 - ty1);
                float iou = inter / (ta + aarea - inter);
                if (iou > bestOv) bestOv = iou;
            }
            if (!(bestOv > 0.5f)) {
                // ph branch: label/encode from truth t vs anchor pp
                float x1 = tg[t * 5 + 0], y1 = tg[t * 5 + 1];
                float x2 = tg[t * 5 + 2], y2 = tg[t * 5 + 3];
                int lbl = (int)tg[t * 5 + 4];     // >= 1
                float cx = (x1 + x2) * 0.5f, cy = (y1 + y2) * 0.5f;
                float ww = x2 - x1, hh = y2 - y1;
                float e0 = (cx - a.x) / a.z;
                float e1 = (cy - a.y) / a.w;
                float e2 = logf(ww) - logf(a.z);
                float e3 = logf(hh) - logf(a.w);
                float4 lp = ((const float4*)loc)[(size_t)b * P + pp];
                float locC = sl1(lp.x - e0) + sl1(lp.y - e1) + sl1(lp.z - e2) + sl1(lp.w - e3);
                dLoc = (double)locC;
                dPos = 1;
                const float* c = conf + ((size_t)b * P + pp) * (size_t)NC;
                float s0 = 0.0f, s1 = 0.0f, s2 = 0.0f, s3 = 0.0f;
                #pragma unroll
                for (int k = 0; k < 20; ++k) {
                    s0 += __expf(c[4 * k + 0]);
                    s1 += __expf(c[4 * k + 1]);
                    s2 += __expf(c[4 * k + 2]);
                    s3 += __expf(c[4 * k + 3]);
                }
                s0 += __expf(c[80]);
                float lse = __logf((s0 + s1) + (s2 + s3));
                float xs = c[lbl];
                dCls = (double)(lse - xs);
                closs[(size_t)b * P + pp] = 0.0f;  // pos prior -> closs 0 (matches ref)
            }
        }
    }
    // wave-0 reduce (deltas live in lanes 0..23 only)
    #pragma unroll
    for (int off = 32; off > 0; off >>= 1) {
        dLoc += __shfl_down(dLoc, off, 64);
        dCls += __shfl_down(dCls, off, 64);
        dPos += __shfl_down(dPos, off, 64);
    }
    if (tid == 0) {
        if (dLoc != 0.0) atomicAdd(&acc[0], dLoc);
        if (dCls != 0.0) atomicAdd(&acc[1], dCls);
        if (dPos) atomicAdd(&numPos[b], dPos);
    }
}

// K3: per-batch radix-select K-th largest closs, sum of top-K (tie-invariant)
__global__ __launch_bounds__(1024) void k_select(
        const float* __restrict__ closs, const int* __restrict__ numPos,
        double* __restrict__ acc) {
    int b = blockIdx.x;
    int tid = threadIdx.x;
    int np = numPos[b];
    long long Kl = 3LL * np;
    int K = (int)(Kl < (long long)(P - 1) ? Kl : (long long)(P - 1));
    if (K <= 0) return;
    const float* row = closs + (size_t)b * P;
    __shared__ unsigned int hist[256];
    __shared__ unsigned int s_prefix;
    __shared__ int s_rem;
    __shared__ double sred[16];
    __shared__ int cred[16];
    if (tid == 0) { s_prefix = 0; s_rem = K; }
    __syncthreads();
    for (int rd = 3; rd >= 0; --rd) {
        if (tid < 256) hist[tid] = 0;
        __syncthreads();
        unsigned int prefix = s_prefix;
        int rem = s_rem;
        for (int i = tid; i < P; i += 1024) {
            unsigned int bits = __float_as_uint(row[i]);
            if (rd == 3 || (bits >> ((rd + 1) * 8)) == prefix)
                atomicAdd(&hist[(bits >> (rd * 8)) & 0xFFu], 1u);
        }
        __syncthreads();
        if (tid < 64) {
            unsigned int h0 = hist[4 * tid + 0], h1 = hist[4 * tid + 1];
            unsigned int h2 = hist[4 * tid + 2], h3 = hist[4 * tid + 3];
            unsigned int S = h0 + h1 + h2 + h3;
            #pragma unroll
            for (int off = 1; off < 64; off <<= 1) {   // inclusive suffix scan
                unsigned int up = __shfl_down(S, off, 64);
                if (tid + off < 64) S += up;
            }
            unsigned int above = __shfl_down(S, 1, 64);
            if (tid == 63) above = 0;
            if ((unsigned)rem <= S && (unsigned)rem > above) {
                int rr = rem - (int)above;
                int digit;
                if (rr <= (int)h3) digit = 4 * tid + 3;
                else { rr -= h3;
                    if (rr <= (int)h2) digit = 4 * tid + 2;
                    else { rr -= h2;
                        if (rr <= (int)h1) digit = 4 * tid + 1;
                        else { rr -= h1; digit = 4 * tid; } } }
                s_prefix = (prefix << 8) | (unsigned)digit;
                s_rem = rr;
            }
        }
        __syncthreads();
    }
    unsigned int tbits = s_prefix;
    float tval = __uint_as_float(tbits);
    int cg = 0;
    double sg = 0.0;
    for (int i = tid; i < P; i += 1024) {
        float v = row[i];
        if (__float_as_uint(v) > tbits) { cg++; sg += (double)v; }
    }
    int lane = tid & 63, w = tid >> 6;
    #pragma unroll
    for (int off = 32; off > 0; off >>= 1) {
        sg += __shfl_down(sg, off, 64);
        cg += __shfl_down(cg, off, 64);
    }
    if (lane == 0) { sred[w] = sg; cred[w] = cg; }
    __syncthreads();
    if (tid == 0) {
        double sgT = 0.0; int cgT = 0;
        #pragma unroll
        for (int i = 0; i < 16; ++i) { sgT += sred[i]; cgT += cred[i]; }
        atomicAdd(&acc[2], sgT + (double)(K - cgT) * (double)tval);
    }
}

// K4: finalize
__global__ void k_final(const int* __restrict__ numPos, const double* __restrict__ acc,
                        float* __restrict__ out) {
    int lane = threadIdx.x;  // 64 threads, B=64
    int np = numPos[lane];
    long long Kl = 3LL * np;
    long long K = Kl < (long long)(P - 1) ? Kl : (long long)(P - 1);
    long long sel = (long long)np + K;  // pos/neg disjoint
    int N = np;
    #pragma unroll
    for (int off = 32; off > 0; off >>= 1) {
        N += __shfl_down(N, off, 64);
        sel += __shfl_down(sel, off, 64);
    }
    if (lane == 0) {
        double n = (double)N;
        double nonsel = (double)((long long)B * (long long)P - sel);
        double cls = acc[1] + acc[2] + nonsel * 4.3944491546724391;  // ln(81)
        out[0] = (float)(acc[0] / n);
        out[1] = (float)(cls / n);
    }
}

extern "C" void kernel_launch(void* const* d_in, const int* in_sizes, int n_in,
                              void* d_out, int out_size, void* d_ws, size_t ws_size,
                              hipStream_t stream) {
    const float* loc     = (const float*)d_in[0];
    const float* conf    = (const float*)d_in[1];
    const float* targets = (const float*)d_in[2];
    const float* anchors = (const float*)d_in[3];
    float* out = (float*)d_out;
    char* ws = (char*)d_ws;

    float* closs  = (float*)(ws + OFF_CLOSS);
    unsigned long long* bpk = (unsigned long long*)(ws + OFF_BPK);
    int* numPos   = (int*)(ws + OFF_NUMPOS);
    double* acc   = (double*)(ws + OFF_ACC);

    k_init<<<6, 256, 0, stream>>>(bpk, numPos, acc);
    dim3 g1((P + 255) / 256, B);
    k_main<<<g1, 256, 0, stream>>>(loc, conf, targets, anchors, bpk,
                                   closs, numPos, acc);
    k_fix<<<B, 128, 0, stream>>>(loc, conf, targets, anchors, bpk,
                                 closs, numPos, acc);
    k_select<<<B, 1024, 0, stream>>>(closs, numPos, acc);
    k_final<<<1, 64, 0, stream>>>(numPos, acc, out);
}